// Round 1
// baseline (31270.450 us; speedup 1.0000x reference)
//
#include <hip/hip_runtime.h>
#include <hip/hip_bf16.h>
#include <math.h>

// Problem constants
constexpr int Lc  = 4;
constexpr int Bc  = 2;
constexpr int Sc  = 2048;
constexpr int Dc  = 1024;
constexpr int Hc  = 16;
constexpr int Vc  = 50257;
constexpr int Fc  = 4096;
constexpr int DHc = 64;
constexpr int Mr  = Bc * Sc;   // 4096 rows of the token stream

// ---------------------------------------------------------------------------
// Embedding: x[row] = word_emb[tokens[row]] + pos_emb[row % S]
// ---------------------------------------------------------------------------
__global__ void embed_kernel(const int* __restrict__ tokens,
                             const float* __restrict__ we,
                             const float* __restrict__ pe,
                             float* __restrict__ x) {
    int row = blockIdx.x;                 // 0..Mr-1 = b*S+s
    int s   = row & (Sc - 1);
    int tok = tokens[row];
    const float* wp = we + (size_t)tok * Dc;
    const float* pp = pe + (size_t)s * Dc;
    float* xp = x + (size_t)row * Dc;
    for (int i = threadIdx.x; i < Dc; i += blockDim.x)
        xp[i] = wp[i] + pp[i];
}

// ---------------------------------------------------------------------------
// LayerNorm (one block per row, D=1024). Safe in-place (out may == x).
// ---------------------------------------------------------------------------
__global__ __launch_bounds__(256) void ln_kernel(const float* __restrict__ x,
                                                 const float* __restrict__ w,
                                                 const float* __restrict__ b,
                                                 float* __restrict__ out) {
    __shared__ float red[256];
    int row = blockIdx.x;
    int tid = threadIdx.x;
    const float* xp = x + (size_t)row * Dc;
    float s1 = 0.f, s2 = 0.f;
    for (int i = tid; i < Dc; i += 256) {
        float v = xp[i];
        s1 += v;
        s2 += v * v;
    }
    red[tid] = s1; __syncthreads();
    for (int off = 128; off > 0; off >>= 1) {
        if (tid < off) red[tid] += red[tid + off];
        __syncthreads();
    }
    float mean = red[0] * (1.0f / Dc);
    __syncthreads();
    red[tid] = s2; __syncthreads();
    for (int off = 128; off > 0; off >>= 1) {
        if (tid < off) red[tid] += red[tid + off];
        __syncthreads();
    }
    float var  = red[0] * (1.0f / Dc) - mean * mean;
    float rstd = rsqrtf(var + 1e-5f);
    float* op = out + (size_t)row * Dc;
    for (int i = tid; i < Dc; i += 256)
        op[i] = (xp[i] - mean) * rstd * w[i] + b[i];
}

// ---------------------------------------------------------------------------
// Tiled fp32 GEMM: C = act(A @ B + bias [+ Cin]).
// A [M,K] row-major, B [K,N] row-major. M,N multiples of 64; K multiple of 16.
// act: 0 = none, 1 = exact GELU. addC: add Cin elementwise (residual; may
// alias C — each element read exactly once by its writer thread).
// ---------------------------------------------------------------------------
__global__ __launch_bounds__(256) void gemm_kernel(const float* __restrict__ A,
                                                   const float* __restrict__ Bm,
                                                   const float* __restrict__ bias,
                                                   const float* __restrict__ Cin,
                                                   float* __restrict__ C,
                                                   int M, int N, int K,
                                                   int act, int addC) {
    __shared__ __align__(16) float As[16][64];
    __shared__ __align__(16) float Bs[16][64];
    int tid = threadIdx.x;
    int tx = tid & 15, ty = tid >> 4;
    int rowBase = blockIdx.y * 64;
    int colBase = blockIdx.x * 64;

    float acc[4][4] = {{0.f}};

    for (int k0 = 0; k0 < K; k0 += 16) {
        #pragma unroll
        for (int i = 0; i < 4; i++) {
            int idx = tid + i * 256;
            int ar = idx >> 4, ac = idx & 15;
            As[ac][ar] = A[(size_t)(rowBase + ar) * K + k0 + ac];
            int br = idx >> 6, bc = idx & 63;
            Bs[br][bc] = Bm[(size_t)(k0 + br) * N + colBase + bc];
        }
        __syncthreads();
        #pragma unroll
        for (int kk = 0; kk < 16; kk++) {
            float4 a4 = *(const float4*)(&As[kk][ty * 4]);
            float4 b4 = *(const float4*)(&Bs[kk][tx * 4]);
            float av[4] = {a4.x, a4.y, a4.z, a4.w};
            float bv[4] = {b4.x, b4.y, b4.z, b4.w};
            #pragma unroll
            for (int i = 0; i < 4; i++)
                #pragma unroll
                for (int j = 0; j < 4; j++)
                    acc[i][j] += av[i] * bv[j];
        }
        __syncthreads();
    }

    #pragma unroll
    for (int i = 0; i < 4; i++) {
        int r = rowBase + ty * 4 + i;
        #pragma unroll
        for (int j = 0; j < 4; j++) {
            int c = colBase + tx * 4 + j;
            float v = acc[i][j] + bias[c];
            if (addC) v += Cin[(size_t)r * N + c];
            if (act)  v = 0.5f * v * (1.0f + erff(v * 0.70710678118654752f));
            C[(size_t)r * N + c] = v;
        }
    }
}

// ---------------------------------------------------------------------------
// RoPE applied in-place to q and k, layout [B,S,H,DH] (== [B,S,D]).
// Half-split rotation: out[j] = x1*cos - x2*sin ; out[j+32] = x2*cos + x1*sin.
// ---------------------------------------------------------------------------
__global__ void rope_kernel(float* __restrict__ q, float* __restrict__ k) {
    int p = blockIdx.x * blockDim.x + threadIdx.x;
    if (p >= Bc * Sc * Hc * (DHc / 2)) return;
    int j    = p & 31;
    int h    = (p >> 5) & (Hc - 1);
    int srow = p >> 9;                 // b*S + s   (H * DH/2 = 512 = 2^9)
    int s    = srow & (Sc - 1);
    float inv = powf(10000.0f, -(float)(2 * j) * (1.0f / 64.0f));
    float fr  = (float)s * inv;
    float c = cosf(fr), sn = sinf(fr);
    size_t base = (size_t)srow * Dc + h * DHc;
    float x1 = q[base + j], x2 = q[base + j + 32];
    q[base + j]      = x1 * c - x2 * sn;
    q[base + j + 32] = x2 * c + x1 * sn;
    x1 = k[base + j]; x2 = k[base + j + 32];
    k[base + j]      = x1 * c - x2 * sn;
    k[base + j + 32] = x2 * c + x1 * sn;
}

// ---------------------------------------------------------------------------
// Causal attention, one block per (b, h, q). Scores for the whole row live in
// LDS (<= 2048 floats). Two-pass softmax, then weighted V accumulation.
// ---------------------------------------------------------------------------
__global__ __launch_bounds__(256) void attn_kernel(const float* __restrict__ q,
                                                   const float* __restrict__ k,
                                                   const float* __restrict__ v,
                                                   float* __restrict__ o) {
    __shared__ float sc[Sc];               // 8 KB
    __shared__ __align__(16) float qs[DHc];
    __shared__ float red[256];
    __shared__ float red2[4][DHc];
    int blk = blockIdx.x;
    int qi  = blk & (Sc - 1);
    int bh  = blk >> 11;                   // S = 2048 = 2^11
    int h   = bh & (Hc - 1);
    int b   = bh >> 4;
    int tid = threadIdx.x;
    size_t qbase = ((size_t)(b * Sc + qi)) * Dc + h * DHc;
    if (tid < DHc) qs[tid] = q[qbase + tid];
    __syncthreads();

    int nk = qi + 1;
    float lmax = -1e30f;
    for (int kk = tid; kk < nk; kk += 256) {
        const float* kp = k + ((size_t)(b * Sc + kk)) * Dc + h * DHc;
        float dot = 0.f;
        #pragma unroll
        for (int d = 0; d < DHc; d += 4) {
            float4 kv = *(const float4*)(kp + d);
            float4 qv = *(const float4*)(qs + d);
            dot += qv.x * kv.x + qv.y * kv.y + qv.z * kv.z + qv.w * kv.w;
        }
        dot *= 0.125f;                     // 1/sqrt(64)
        sc[kk] = dot;
        lmax = fmaxf(lmax, dot);
    }
    red[tid] = lmax; __syncthreads();
    for (int off = 128; off > 0; off >>= 1) {
        if (tid < off) red[tid] = fmaxf(red[tid], red[tid + off]);
        __syncthreads();
    }
    float m = red[0];
    __syncthreads();

    float lsum = 0.f;
    for (int kk = tid; kk < nk; kk += 256) {
        float p = expf(sc[kk] - m);
        sc[kk] = p;
        lsum += p;
    }
    red[tid] = lsum; __syncthreads();
    for (int off = 128; off > 0; off >>= 1) {
        if (tid < off) red[tid] += red[tid + off];
        __syncthreads();
    }
    float invs = 1.0f / red[0];

    int d = tid & 63, part = tid >> 6;     // 4 partial accumulators per d
    float acc = 0.f;
    for (int kk = part; kk < nk; kk += 4)
        acc += sc[kk] * v[((size_t)(b * Sc + kk)) * Dc + h * DHc + d];
    red2[part][d] = acc; __syncthreads();
    if (part == 0)
        o[qbase + d] = (red2[0][d] + red2[1][d] + red2[2][d] + red2[3][d]) * invs;
}

// ---------------------------------------------------------------------------
// Fused head: per block, 8 rows. Streams head_w [D,V] once per block with
// online logsumexp; captures target logit; writes per-row NLL. Never
// materializes logits.
// ---------------------------------------------------------------------------
constexpr int HROWS = 8;
constexpr int VPT   = 4;
__global__ __launch_bounds__(256) void head_kernel(const float* __restrict__ x,
                                                   const float* __restrict__ W,
                                                   const int* __restrict__ targets,
                                                   float* __restrict__ nll) {
    __shared__ __align__(16) float xs[HROWS * Dc];   // 32 KB
    __shared__ float redm[256], reds[256];
    __shared__ float tlog[HROWS];
    __shared__ int   tgt[HROWS];
    int rb  = blockIdx.x * HROWS;
    int tid = threadIdx.x;
    for (int i = tid; i < HROWS * Dc; i += 256)
        xs[i] = x[(size_t)rb * Dc + i];
    if (tid < HROWS) { tgt[tid] = targets[rb + tid]; tlog[tid] = 0.f; }
    __syncthreads();

    float m[HROWS], ssum[HROWS];
    #pragma unroll
    for (int r = 0; r < HROWS; r++) { m[r] = -1e30f; ssum[r] = 0.f; }

    for (int vb = 0; vb < Vc; vb += 256 * VPT) {
        int vidx[VPT], vcl[VPT];
        bool vok[VPT];
        #pragma unroll
        for (int i = 0; i < VPT; i++) {
            vidx[i] = vb + tid + i * 256;
            vok[i]  = vidx[i] < Vc;
            vcl[i]  = vok[i] ? vidx[i] : 0;
        }
        float acc[HROWS][VPT];
        #pragma unroll
        for (int r = 0; r < HROWS; r++)
            #pragma unroll
            for (int i = 0; i < VPT; i++) acc[r][i] = 0.f;

        for (int d = 0; d < Dc; d += 4) {
            float4 xr[HROWS];
            #pragma unroll
            for (int r = 0; r < HROWS; r++)
                xr[r] = *(const float4*)(&xs[r * Dc + d]);
            #pragma unroll
            for (int dd = 0; dd < 4; dd++) {
                float wv[VPT];
                #pragma unroll
                for (int i = 0; i < VPT; i++)
                    wv[i] = W[(size_t)(d + dd) * Vc + vcl[i]];
                #pragma unroll
                for (int r = 0; r < HROWS; r++) {
                    float xv = (dd == 0) ? xr[r].x : (dd == 1) ? xr[r].y
                             : (dd == 2) ? xr[r].z : xr[r].w;
                    #pragma unroll
                    for (int i = 0; i < VPT; i++)
                        acc[r][i] += xv * wv[i];
                }
            }
        }
        #pragma unroll
        for (int i = 0; i < VPT; i++) {
            if (!vok[i]) continue;
            #pragma unroll
            for (int r = 0; r < HROWS; r++) {
                float scv = acc[r][i];
                if (vidx[i] == tgt[r]) tlog[r] = scv;
                float mn = fmaxf(m[r], scv);
                ssum[r] = ssum[r] * expf(m[r] - mn) + expf(scv - mn);
                m[r] = mn;
            }
        }
    }

    for (int r = 0; r < HROWS; r++) {
        redm[tid] = m[r]; reds[tid] = ssum[r];
        __syncthreads();
        for (int off = 128; off > 0; off >>= 1) {
            if (tid < off) {
                float m1 = redm[tid], m2 = redm[tid + off];
                float mn = fmaxf(m1, m2);
                reds[tid] = reds[tid] * expf(m1 - mn) + reds[tid + off] * expf(m2 - mn);
                redm[tid] = mn;
            }
            __syncthreads();
        }
        if (tid == 0)
            nll[rb + r] = redm[0] + logf(reds[0]) - tlog[r];
        __syncthreads();
    }
}

// ---------------------------------------------------------------------------
// Final mean over the 4096 per-row NLLs.
// ---------------------------------------------------------------------------
__global__ __launch_bounds__(256) void loss_kernel(const float* __restrict__ nll,
                                                   float* __restrict__ out) {
    __shared__ float red[256];
    int tid = threadIdx.x;
    float s = 0.f;
    for (int i = tid; i < Mr; i += 256) s += nll[i];
    red[tid] = s; __syncthreads();
    for (int off = 128; off > 0; off >>= 1) {
        if (tid < off) red[tid] += red[tid + off];
        __syncthreads();
    }
    if (tid == 0) out[0] = red[0] * (1.0f / Mr);
}

// ---------------------------------------------------------------------------
// Host launch
// ---------------------------------------------------------------------------
extern "C" void kernel_launch(void* const* d_in, const int* in_sizes, int n_in,
                              void* d_out, int out_size, void* d_ws, size_t ws_size,
                              hipStream_t stream) {
    const int*   tokens   = (const int*)  d_in[0];
    const int*   targets  = (const int*)  d_in[1];
    const float* word_emb = (const float*)d_in[2];
    const float* pos_emb  = (const float*)d_in[3];
    const float* ln1_w    = (const float*)d_in[4];
    const float* ln1_b    = (const float*)d_in[5];
    const float* wq       = (const float*)d_in[6];
    const float* bq       = (const float*)d_in[7];
    const float* wk       = (const float*)d_in[8];
    const float* bk       = (const float*)d_in[9];
    const float* wv       = (const float*)d_in[10];
    const float* bv       = (const float*)d_in[11];
    const float* wo       = (const float*)d_in[12];
    const float* bo       = (const float*)d_in[13];
    const float* ln2_w    = (const float*)d_in[14];
    const float* ln2_b    = (const float*)d_in[15];
    const float* w1       = (const float*)d_in[16];
    const float* b1       = (const float*)d_in[17];
    const float* w2       = (const float*)d_in[18];
    const float* b2       = (const float*)d_in[19];
    const float* post_w   = (const float*)d_in[20];
    const float* post_b   = (const float*)d_in[21];
    const float* lnf_w    = (const float*)d_in[22];
    const float* lnf_b    = (const float*)d_in[23];
    const float* head_w   = (const float*)d_in[24];

    // Workspace layout (floats): x|h|q|k|v|mid|nll  (~144 MB total)
    float* ws  = (float*)d_ws;
    size_t SZ  = (size_t)Mr * Dc;          // 4M floats
    float* x   = ws;
    float* h   = x + SZ;
    float* q   = h + SZ;
    float* k   = q + SZ;
    float* v   = k + SZ;
    float* mid = v + SZ;                   // [Mr, F] = 16M floats
    float* nll = mid + (size_t)Mr * Fc;

    dim3 blk(256);
    dim3 gemmDD(Dc / 64, Mr / 64);         // N=1024
    dim3 gemmDF(Fc / 64, Mr / 64);         // N=4096

    embed_kernel<<<Mr, blk, 0, stream>>>(tokens, word_emb, pos_emb, x);

    for (int l = 0; l < Lc; l++) {
        const float* Wq = wq + (size_t)l * Dc * Dc;
        const float* Wk = wk + (size_t)l * Dc * Dc;
        const float* Wv = wv + (size_t)l * Dc * Dc;
        const float* Wo = wo + (size_t)l * Dc * Dc;
        const float* W1 = w1 + (size_t)l * Dc * Fc;
        const float* W2 = w2 + (size_t)l * Fc * Dc;

        ln_kernel<<<Mr, blk, 0, stream>>>(x, ln1_w + l * Dc, ln1_b + l * Dc, h);
        gemm_kernel<<<gemmDD, blk, 0, stream>>>(h, Wq, bq + l * Dc, nullptr, q,
                                                Mr, Dc, Dc, 0, 0);
        gemm_kernel<<<gemmDD, blk, 0, stream>>>(h, Wk, bk + l * Dc, nullptr, k,
                                                Mr, Dc, Dc, 0, 0);
        gemm_kernel<<<gemmDD, blk, 0, stream>>>(h, Wv, bv + l * Dc, nullptr, v,
                                                Mr, Dc, Dc, 0, 0);
        rope_kernel<<<(Bc * Sc * Hc * 32 + 255) / 256, blk, 0, stream>>>(q, k);
        attn_kernel<<<Bc * Hc * Sc, blk, 0, stream>>>(q, k, v, h);
        gemm_kernel<<<gemmDD, blk, 0, stream>>>(h, Wo, bo + l * Dc, x, x,
                                                Mr, Dc, Dc, 0, 1);
        ln_kernel<<<Mr, blk, 0, stream>>>(x, ln2_w + l * Dc, ln2_b + l * Dc, h);
        gemm_kernel<<<gemmDF, blk, 0, stream>>>(h, W1, b1 + l * Fc, nullptr, mid,
                                                Mr, Fc, Dc, 1, 0);
        gemm_kernel<<<gemmDD, blk, 0, stream>>>(mid, W2, b2 + l * Dc, x, x,
                                                Mr, Dc, Fc, 0, 1);
        if (l == Lc - 1)
            ln_kernel<<<Mr, blk, 0, stream>>>(x, post_w, post_b, x);
    }

    ln_kernel<<<Mr, blk, 0, stream>>>(x, lnf_w, lnf_b, x);
    head_kernel<<<Mr / HROWS, blk, 0, stream>>>(x, head_w, targets, nll);
    loss_kernel<<<1, blk, 0, stream>>>(nll, (float*)d_out);
}

// Round 2
// 15675.583 us; speedup vs baseline: 1.9949x; 1.9949x over previous
//
#include <hip/hip_runtime.h>
#include <hip/hip_bf16.h>
#include <math.h>
#include <stdint.h>

// Problem constants
constexpr int Lc  = 4;
constexpr int Bc  = 2;
constexpr int Sc  = 2048;
constexpr int Dc  = 1024;
constexpr int Hc  = 16;
constexpr int Vc  = 50257;
constexpr int Fc  = 4096;
constexpr int DHc = 64;
constexpr int Mr  = Bc * Sc;       // 4096 token rows
constexpr int QKVN = 3 * Dc;       // 3072 fused QKV width
constexpr int Vpad = 50304;        // vocab padded to 128*393
constexpr int NVT  = Vpad / 128;   // 393 vocab tiles

typedef __attribute__((ext_vector_type(8))) short short8;   // 8 bf16 (4 VGPRs)
typedef __attribute__((ext_vector_type(4))) float f32x4;

// async global->LDS, 16 B per lane; LDS dest must be wave-uniform base + lane*16
__device__ __forceinline__ void gl2lds16(const __hip_bfloat16* g, __hip_bfloat16* l) {
    __builtin_amdgcn_global_load_lds(
        (const uint32_t __attribute__((address_space(1)))*)g,
        (uint32_t __attribute__((address_space(3)))*)l, 16, 0, 0);
}

__device__ __forceinline__ void lse_combine(float& m, float& s, float mo, float so) {
    float mn = fmaxf(m, mo);
    s = s * expf(m - mn) + so * expf(mo - mn);
    m = mn;
}

// ---------------------------------------------------------------------------
// Embedding
// ---------------------------------------------------------------------------
__global__ void embed_kernel(const int* __restrict__ tokens,
                             const float* __restrict__ we,
                             const float* __restrict__ pe,
                             float* __restrict__ x) {
    int row = blockIdx.x;
    int s   = row & (Sc - 1);
    int tok = tokens[row];
    const float* wp = we + (size_t)tok * Dc;
    const float* pp = pe + (size_t)s * Dc;
    float* xp = x + (size_t)row * Dc;
    for (int i = threadIdx.x; i < Dc; i += blockDim.x)
        xp[i] = wp[i] + pp[i];
}

// ---------------------------------------------------------------------------
// LayerNorm; optional fp32 and/or bf16 outputs. Safe in-place for outF==x.
// ---------------------------------------------------------------------------
__global__ __launch_bounds__(256) void ln_kernel(const float* __restrict__ x,
                                                 const float* __restrict__ w,
                                                 const float* __restrict__ b,
                                                 float* __restrict__ outF,
                                                 __hip_bfloat16* __restrict__ outB) {
    __shared__ float red[256];
    int row = blockIdx.x;
    int tid = threadIdx.x;
    const float* xp = x + (size_t)row * Dc;
    float s1 = 0.f, s2 = 0.f;
    for (int i = tid; i < Dc; i += 256) {
        float v = xp[i];
        s1 += v; s2 += v * v;
    }
    red[tid] = s1; __syncthreads();
    for (int off = 128; off > 0; off >>= 1) {
        if (tid < off) red[tid] += red[tid + off];
        __syncthreads();
    }
    float mean = red[0] * (1.0f / Dc);
    __syncthreads();
    red[tid] = s2; __syncthreads();
    for (int off = 128; off > 0; off >>= 1) {
        if (tid < off) red[tid] += red[tid + off];
        __syncthreads();
    }
    float var  = red[0] * (1.0f / Dc) - mean * mean;
    float rstd = rsqrtf(var + 1e-5f);
    for (int i = tid; i < Dc; i += 256) {
        float v = (xp[i] - mean) * rstd * w[i] + b[i];
        if (outF) outF[(size_t)row * Dc + i] = v;
        if (outB) outB[(size_t)row * Dc + i] = __float2bfloat16(v);
    }
}

// ---------------------------------------------------------------------------
// Weight transpose + bf16 convert: W [K][srcN] f32 -> Wt [dstN][K] bf16,
// rows >= srcN zero-filled. Grid (dstN/32, K/32), block 256.
// ---------------------------------------------------------------------------
__global__ __launch_bounds__(256) void convw_kernel(const float* __restrict__ W,
                                                    __hip_bfloat16* __restrict__ Wt,
                                                    int K, int srcN) {
    __shared__ float t[32][33];
    int n0 = blockIdx.x * 32, k0 = blockIdx.y * 32;
    int tx = threadIdx.x & 31, ty = threadIdx.x >> 5;
    #pragma unroll
    for (int j = 0; j < 4; j++) {
        int k = k0 + ty + j * 8, n = n0 + tx;
        t[ty + j * 8][tx] = (n < srcN) ? W[(size_t)k * srcN + n] : 0.f;
    }
    __syncthreads();
    #pragma unroll
    for (int j = 0; j < 4; j++) {
        int n = n0 + ty + j * 8, k = k0 + tx;
        Wt[(size_t)n * K + k] = __float2bfloat16(t[tx][ty + j * 8]);
    }
}

__global__ void bcat_kernel(const float* __restrict__ bq, const float* __restrict__ bk,
                            const float* __restrict__ bv, float* __restrict__ o) {
    int i = blockIdx.x * 256 + threadIdx.x;
    if (i < QKVN)
        o[i] = (i < Dc) ? bq[i] : (i < 2 * Dc) ? bk[i - Dc] : bv[i - 2 * Dc];
}

// ---------------------------------------------------------------------------
// bf16 MFMA GEMM (m97 structure): C = act(A @ Bt^T + bias [+ Cin]).
// A [M][K] bf16, Bt [N][K] bf16 (i.e. B transposed). Tile 128x128, BK=32.
// Outputs fp32 (outF) and/or bf16 (outB). M,N mult of 128, K mult of 32.
// ---------------------------------------------------------------------------
__global__ __launch_bounds__(256) void bgemm_kernel(
    const __hip_bfloat16* __restrict__ A,
    const __hip_bfloat16* __restrict__ Bt,
    const float* __restrict__ bias,
    const float* __restrict__ Cin,
    float* __restrict__ outF,
    __hip_bfloat16* __restrict__ outB,
    int N, int K, int act) {
    __shared__ __align__(16) __hip_bfloat16 As[128 * 32];
    __shared__ __align__(16) __hip_bfloat16 Bs[128 * 32];
    const int tid = threadIdx.x;
    const int rowBase = blockIdx.y * 128;
    const int colBase = blockIdx.x * 128;
    const int w = tid >> 6, lane = tid & 63;
    const int wm = w >> 1, wn = w & 1;
    const int quad = lane >> 4, l16 = lane & 15;

    f32x4 acc[4][4];
    #pragma unroll
    for (int i = 0; i < 4; i++)
        #pragma unroll
        for (int j = 0; j < 4; j++) acc[i][j] = (f32x4){0.f, 0.f, 0.f, 0.f};

    const __hip_bfloat16* a0 = A  + (size_t)(rowBase + (tid >> 2)) * K + (tid & 3) * 8;
    const __hip_bfloat16* b0 = Bt + (size_t)(colBase + (tid >> 2)) * K + (tid & 3) * 8;
    const size_t rstep = (size_t)64 * K;
    __hip_bfloat16* lA = As + tid * 8;
    __hip_bfloat16* lB = Bs + tid * 8;

    for (int k0 = 0; k0 < K; k0 += 32) {
        __syncthreads();
        gl2lds16(a0 + k0,         lA);
        gl2lds16(a0 + k0 + rstep, lA + 2048);
        gl2lds16(b0 + k0,         lB);
        gl2lds16(b0 + k0 + rstep, lB + 2048);
        __syncthreads();

        short8 af[4], bf[4];
        #pragma unroll
        for (int i = 0; i < 4; i++) {
            af[i] = *(const short8*)(As + (wm * 64 + i * 16 + l16) * 32 + quad * 8);
            bf[i] = *(const short8*)(Bs + (wn * 64 + i * 16 + l16) * 32 + quad * 8);
        }
        #pragma unroll
        for (int i = 0; i < 4; i++)
            #pragma unroll
            for (int j = 0; j < 4; j++)
                acc[i][j] = __builtin_amdgcn_mfma_f32_16x16x32_bf16(af[i], bf[j], acc[i][j], 0, 0, 0);
    }

    #pragma unroll
    for (int i = 0; i < 4; i++) {
        #pragma unroll
        for (int j = 0; j < 4; j++) {
            int col = colBase + wn * 64 + j * 16 + l16;
            float bb = bias ? bias[col] : 0.f;
            #pragma unroll
            for (int r = 0; r < 4; r++) {
                int row = rowBase + wm * 64 + i * 16 + quad * 4 + r;
                float v = acc[i][j][r] + bb;
                if (Cin) v += Cin[(size_t)row * N + col];
                if (act) v = 0.5f * v * (1.0f + erff(v * 0.70710678118654752f));
                if (outF) outF[(size_t)row * N + col] = v;
                if (outB) outB[(size_t)row * N + col] = __float2bfloat16(v);
            }
        }
    }
}

// ---------------------------------------------------------------------------
// Head GEMM (same core) with fused per-row partial logsumexp over the block's
// 128 vocab cols + target-logit capture. Logits never hit global memory.
// Grid (NVT, Mr/128). Partials: pmax/psum [NVT][Mr].
// ---------------------------------------------------------------------------
__global__ __launch_bounds__(256) void headgemm_kernel(
    const __hip_bfloat16* __restrict__ A,
    const __hip_bfloat16* __restrict__ Bt,
    const int* __restrict__ targets,
    float* __restrict__ pmax, float* __restrict__ psum,
    float* __restrict__ tlog) {
    __shared__ __align__(16) __hip_bfloat16 As[128 * 32];
    __shared__ __align__(16) __hip_bfloat16 Bs[128 * 32];
    __shared__ float pmW[2][128], psW[2][128];
    __shared__ int tg[128];
    const int tid = threadIdx.x;
    const int rowBase = blockIdx.y * 128;
    const int colBase = blockIdx.x * 128;
    const int K = Dc;
    const int w = tid >> 6, lane = tid & 63;
    const int wm = w >> 1, wn = w & 1;
    const int quad = lane >> 4, l16 = lane & 15;

    if (tid < 128) tg[tid] = targets[rowBase + tid];

    f32x4 acc[4][4];
    #pragma unroll
    for (int i = 0; i < 4; i++)
        #pragma unroll
        for (int j = 0; j < 4; j++) acc[i][j] = (f32x4){0.f, 0.f, 0.f, 0.f};

    const __hip_bfloat16* a0 = A  + (size_t)(rowBase + (tid >> 2)) * K + (tid & 3) * 8;
    const __hip_bfloat16* b0 = Bt + (size_t)(colBase + (tid >> 2)) * K + (tid & 3) * 8;
    const size_t rstep = (size_t)64 * K;
    __hip_bfloat16* lA = As + tid * 8;
    __hip_bfloat16* lB = Bs + tid * 8;

    for (int k0 = 0; k0 < K; k0 += 32) {
        __syncthreads();
        gl2lds16(a0 + k0,         lA);
        gl2lds16(a0 + k0 + rstep, lA + 2048);
        gl2lds16(b0 + k0,         lB);
        gl2lds16(b0 + k0 + rstep, lB + 2048);
        __syncthreads();

        short8 af[4], bf[4];
        #pragma unroll
        for (int i = 0; i < 4; i++) {
            af[i] = *(const short8*)(As + (wm * 64 + i * 16 + l16) * 32 + quad * 8);
            bf[i] = *(const short8*)(Bs + (wn * 64 + i * 16 + l16) * 32 + quad * 8);
        }
        #pragma unroll
        for (int i = 0; i < 4; i++)
            #pragma unroll
            for (int j = 0; j < 4; j++)
                acc[i][j] = __builtin_amdgcn_mfma_f32_16x16x32_bf16(af[i], bf[j], acc[i][j], 0, 0, 0);
    }

    #pragma unroll
    for (int i = 0; i < 4; i++) {
        #pragma unroll
        for (int r = 0; r < 4; r++) {
            int rib = wm * 64 + i * 16 + quad * 4 + r;
            float m = -1e30f, s = 0.f;
            float vals[4];
            #pragma unroll
            for (int j = 0; j < 4; j++) {
                int col = colBase + wn * 64 + j * 16 + l16;
                float v = acc[i][j][r];
                bool ok = (col < Vc);
                if (ok && col == tg[rib]) tlog[rowBase + rib] = v;
                vals[j] = ok ? v : -1e30f;
                m = fmaxf(m, vals[j]);
            }
            #pragma unroll
            for (int j = 0; j < 4; j++) s += expf(vals[j] - m);  // masked -> underflow 0
            #pragma unroll
            for (int d = 1; d < 16; d <<= 1) {
                float mo = __shfl_xor(m, d, 64);
                float so = __shfl_xor(s, d, 64);
                lse_combine(m, s, mo, so);
            }
            if (l16 == 0) { pmW[wn][rib] = m; psW[wn][rib] = s; }
        }
    }
    __syncthreads();
    if (tid < 128) {
        float m = pmW[0][tid], s = psW[0][tid];
        lse_combine(m, s, pmW[1][tid], psW[1][tid]);
        pmax[(size_t)blockIdx.x * Mr + rowBase + tid] = m;
        psum[(size_t)blockIdx.x * Mr + rowBase + tid] = s;
    }
}

__global__ __launch_bounds__(256) void head_reduce_kernel(
    const float* __restrict__ pmax, const float* __restrict__ psum,
    const float* __restrict__ tlog, float* __restrict__ nll) {
    __shared__ float rm[256], rs[256];
    int row = blockIdx.x;
    int tid = threadIdx.x;
    float m = -1e30f, s = 0.f;
    for (int t = tid; t < NVT; t += 256)
        lse_combine(m, s, pmax[(size_t)t * Mr + row], psum[(size_t)t * Mr + row]);
    rm[tid] = m; rs[tid] = s; __syncthreads();
    for (int off = 128; off > 0; off >>= 1) {
        if (tid < off) {
            float mm = rm[tid], ss = rs[tid];
            lse_combine(mm, ss, rm[tid + off], rs[tid + off]);
            rm[tid] = mm; rs[tid] = ss;
        }
        __syncthreads();
    }
    if (tid == 0) nll[row] = rm[0] + logf(rs[0]) - tlog[row];
}

// ---------------------------------------------------------------------------
// RoPE in-place on q,k inside fused qkv buffer [Mr][3072].
// ---------------------------------------------------------------------------
__global__ void rope_kernel(float* __restrict__ qkv) {
    int p = blockIdx.x * blockDim.x + threadIdx.x;
    if (p >= Mr * Hc * (DHc / 2)) return;
    int j    = p & 31;
    int h    = (p >> 5) & (Hc - 1);
    int srow = p >> 9;
    int s    = srow & (Sc - 1);
    float inv = powf(10000.0f, -(float)(2 * j) * (1.0f / 64.0f));
    float fr  = (float)s * inv;
    float c = cosf(fr), sn = sinf(fr);
    size_t base = (size_t)srow * QKVN + h * DHc;
    float x1 = qkv[base + j], x2 = qkv[base + j + 32];
    qkv[base + j]      = x1 * c - x2 * sn;
    qkv[base + j + 32] = x2 * c + x1 * sn;
    size_t kb = base + Dc;
    x1 = qkv[kb + j]; x2 = qkv[kb + j + 32];
    qkv[kb + j]      = x1 * c - x2 * sn;
    qkv[kb + j + 32] = x2 * c + x1 * sn;
}

// ---------------------------------------------------------------------------
// Causal attention, one block per (b,h,q); reads fused qkv fp32; writes bf16 o.
// ---------------------------------------------------------------------------
__global__ __launch_bounds__(256) void attn_kernel(const float* __restrict__ qkv,
                                                   __hip_bfloat16* __restrict__ ob) {
    __shared__ float sc[Sc];
    __shared__ __align__(16) float qs[DHc];
    __shared__ float red[256];
    __shared__ float red2[4][DHc];
    int blk = blockIdx.x;
    int qi  = blk & (Sc - 1);
    int bh  = blk >> 11;
    int h   = bh & (Hc - 1);
    int b   = bh >> 4;
    int tid = threadIdx.x;
    size_t qbase = ((size_t)(b * Sc + qi)) * QKVN + h * DHc;
    if (tid < DHc) qs[tid] = qkv[qbase + tid];
    __syncthreads();

    int nk = qi + 1;
    float lmax = -1e30f;
    for (int kk = tid; kk < nk; kk += 256) {
        const float* kp = qkv + ((size_t)(b * Sc + kk)) * QKVN + Dc + h * DHc;
        float dot = 0.f;
        #pragma unroll
        for (int d = 0; d < DHc; d += 4) {
            float4 kv = *(const float4*)(kp + d);
            float4 qv = *(const float4*)(qs + d);
            dot += qv.x * kv.x + qv.y * kv.y + qv.z * kv.z + qv.w * kv.w;
        }
        dot *= 0.125f;
        sc[kk] = dot;
        lmax = fmaxf(lmax, dot);
    }
    red[tid] = lmax; __syncthreads();
    for (int off = 128; off > 0; off >>= 1) {
        if (tid < off) red[tid] = fmaxf(red[tid], red[tid + off]);
        __syncthreads();
    }
    float m = red[0];
    __syncthreads();

    float lsum = 0.f;
    for (int kk = tid; kk < nk; kk += 256) {
        float p = expf(sc[kk] - m);
        sc[kk] = p;
        lsum += p;
    }
    red[tid] = lsum; __syncthreads();
    for (int off = 128; off > 0; off >>= 1) {
        if (tid < off) red[tid] += red[tid + off];
        __syncthreads();
    }
    float invs = 1.0f / red[0];

    int d = tid & 63, part = tid >> 6;
    float acc = 0.f;
    for (int kk = part; kk < nk; kk += 4)
        acc += sc[kk] * qkv[((size_t)(b * Sc + kk)) * QKVN + 2 * Dc + h * DHc + d];
    red2[part][d] = acc; __syncthreads();
    if (part == 0)
        ob[((size_t)(b * Sc + qi)) * Dc + h * DHc + d] =
            __float2bfloat16((red2[0][d] + red2[1][d] + red2[2][d] + red2[3][d]) * invs);
}

__global__ __launch_bounds__(256) void loss_kernel(const float* __restrict__ nll,
                                                   float* __restrict__ out) {
    __shared__ float red[256];
    int tid = threadIdx.x;
    float s = 0.f;
    for (int i = tid; i < Mr; i += 256) s += nll[i];
    red[tid] = s; __syncthreads();
    for (int off = 128; off > 0; off >>= 1) {
        if (tid < off) red[tid] += red[tid + off];
        __syncthreads();
    }
    if (tid == 0) out[0] = red[0] * (1.0f / Mr);
}

// ---------------------------------------------------------------------------
// Host launch
// ---------------------------------------------------------------------------
extern "C" void kernel_launch(void* const* d_in, const int* in_sizes, int n_in,
                              void* d_out, int out_size, void* d_ws, size_t ws_size,
                              hipStream_t stream) {
    const int*   tokens   = (const int*)  d_in[0];
    const int*   targets  = (const int*)  d_in[1];
    const float* word_emb = (const float*)d_in[2];
    const float* pos_emb  = (const float*)d_in[3];
    const float* ln1_w    = (const float*)d_in[4];
    const float* ln1_b    = (const float*)d_in[5];
    const float* wq       = (const float*)d_in[6];
    const float* bq       = (const float*)d_in[7];
    const float* wk       = (const float*)d_in[8];
    const float* bk       = (const float*)d_in[9];
    const float* wv       = (const float*)d_in[10];
    const float* bv       = (const float*)d_in[11];
    const float* wo       = (const float*)d_in[12];
    const float* bo       = (const float*)d_in[13];
    const float* ln2_w    = (const float*)d_in[14];
    const float* ln2_b    = (const float*)d_in[15];
    const float* w1       = (const float*)d_in[16];
    const float* b1       = (const float*)d_in[17];
    const float* w2       = (const float*)d_in[18];
    const float* b2       = (const float*)d_in[19];
    const float* post_w   = (const float*)d_in[20];
    const float* post_b   = (const float*)d_in[21];
    const float* lnf_w    = (const float*)d_in[22];
    const float* lnf_b    = (const float*)d_in[23];
    const float* head_w   = (const float*)d_in[24];

    // Workspace layout (~252 MB)
    float* cur = (float*)d_ws;
    float* x    = cur; cur += (size_t)Mr * Dc;        // 16 MB
    float* qkv  = cur; cur += (size_t)Mr * QKVN;      // 48 MB
    float* nll  = cur; cur += Mr;
    float* tlog = cur; cur += Mr;
    float* bqkv = cur; cur += QKVN;
    float* pmax = cur; cur += (size_t)NVT * Mr;       // 6.4 MB
    float* psum = cur; cur += (size_t)NVT * Mr;       // 6.4 MB
    __hip_bfloat16* bcur = (__hip_bfloat16*)cur;
    __hip_bfloat16* hb     = bcur; bcur += (size_t)Mr * Dc;     // 8 MB
    __hip_bfloat16* ob     = bcur; bcur += (size_t)Mr * Dc;     // 8 MB
    __hip_bfloat16* midb   = bcur; bcur += (size_t)Mr * Fc;     // 32 MB
    __hip_bfloat16* Wqkv_t = bcur; bcur += (size_t)QKVN * Dc;   // 6 MB
    __hip_bfloat16* Wo_t   = bcur; bcur += (size_t)Dc * Dc;     // 2 MB
    __hip_bfloat16* W1_t   = bcur; bcur += (size_t)Fc * Dc;     // 8 MB
    __hip_bfloat16* W2_t   = bcur; bcur += (size_t)Dc * Fc;     // 8 MB
    __hip_bfloat16* Wh_t   = bcur; bcur += (size_t)Vpad * Dc;   // 103 MB

    dim3 blk(256);

    embed_kernel<<<Mr, blk, 0, stream>>>(tokens, word_emb, pos_emb, x);
    // head weight convert (once)
    convw_kernel<<<dim3(Vpad / 32, Dc / 32), blk, 0, stream>>>(head_w, Wh_t, Dc, Vc);

    for (int l = 0; l < Lc; l++) {
        // fused QKV weight: rows [0,1024)=wq^T, [1024,2048)=wk^T, [2048,3072)=wv^T
        convw_kernel<<<dim3(Dc / 32, Dc / 32), blk, 0, stream>>>(wq + (size_t)l * Dc * Dc, Wqkv_t, Dc, Dc);
        convw_kernel<<<dim3(Dc / 32, Dc / 32), blk, 0, stream>>>(wk + (size_t)l * Dc * Dc, Wqkv_t + (size_t)Dc * Dc, Dc, Dc);
        convw_kernel<<<dim3(Dc / 32, Dc / 32), blk, 0, stream>>>(wv + (size_t)l * Dc * Dc, Wqkv_t + (size_t)2 * Dc * Dc, Dc, Dc);
        bcat_kernel<<<QKVN / 256, blk, 0, stream>>>(bq + l * Dc, bk + l * Dc, bv + l * Dc, bqkv);

        ln_kernel<<<Mr, blk, 0, stream>>>(x, ln1_w + l * Dc, ln1_b + l * Dc, nullptr, hb);
        bgemm_kernel<<<dim3(QKVN / 128, Mr / 128), blk, 0, stream>>>(
            hb, Wqkv_t, bqkv, nullptr, qkv, nullptr, QKVN, Dc, 0);
        rope_kernel<<<(Mr * Hc * 32 + 255) / 256, blk, 0, stream>>>(qkv);
        attn_kernel<<<Bc * Hc * Sc, blk, 0, stream>>>(qkv, ob);

        convw_kernel<<<dim3(Dc / 32, Dc / 32), blk, 0, stream>>>(wo + (size_t)l * Dc * Dc, Wo_t, Dc, Dc);
        bgemm_kernel<<<dim3(Dc / 128, Mr / 128), blk, 0, stream>>>(
            ob, Wo_t, bo + l * Dc, x, x, nullptr, Dc, Dc, 0);

        ln_kernel<<<Mr, blk, 0, stream>>>(x, ln2_w + l * Dc, ln2_b + l * Dc, nullptr, hb);
        convw_kernel<<<dim3(Fc / 32, Dc / 32), blk, 0, stream>>>(w1 + (size_t)l * Dc * Fc, W1_t, Dc, Fc);
        bgemm_kernel<<<dim3(Fc / 128, Mr / 128), blk, 0, stream>>>(
            hb, W1_t, b1 + l * Fc, nullptr, nullptr, midb, Fc, Dc, 1);
        convw_kernel<<<dim3(Dc / 32, Fc / 32), blk, 0, stream>>>(w2 + (size_t)l * Fc * Dc, W2_t, Fc, Dc);
        bgemm_kernel<<<dim3(Dc / 128, Mr / 128), blk, 0, stream>>>(
            midb, W2_t, b2 + l * Dc, x, x, nullptr, Dc, Fc, 0);

        if (l == Lc - 1)
            ln_kernel<<<Mr, blk, 0, stream>>>(x, post_w, post_b, x, nullptr);
    }

    ln_kernel<<<Mr, blk, 0, stream>>>(x, lnf_w, lnf_b, nullptr, hb);
    headgemm_kernel<<<dim3(NVT, Mr / 128), blk, 0, stream>>>(hb, Wh_t, targets, pmax, psum, tlog);
    head_reduce_kernel<<<Mr, blk, 0, stream>>>(pmax, psum, tlog, nll);
    loss_kernel<<<1, blk, 0, stream>>>(nll, (float*)d_out);
}